// Round 8
// baseline (679.910 us; speedup 1.0000x reference)
//
#include <hip/hip_runtime.h>
#include <hip/hip_bf16.h>
#include <stdint.h>

// Problem constants (from reference)
#define N_NODES  4096
#define EMB_DIM  512
#define N_HEADS  8
#define K_SPARSE 128
#define HEAD_DIM 64   // EMB_DIM / N_HEADS

typedef __attribute__((ext_vector_type(8))) __bf16 bf16x8;
typedef __attribute__((ext_vector_type(4))) float  f32x4;

__device__ __forceinline__ float bf2f(unsigned short u) {
    union { unsigned int i; float f; } v;
    v.i = ((unsigned int)u) << 16;
    return v.f;
}

__device__ __forceinline__ unsigned short f2bf(float f) {
    // round-to-nearest-even fp32 -> bf16
    union { float f; unsigned int i; } v;
    v.f = f;
    unsigned int x = v.i;
    unsigned int rounding = 0x7fffu + ((x >> 16) & 1u);
    x += rounding;
    return (unsigned short)(x >> 16);
}

// ---------------------------------------------------------------------------
// Kernel 1: fused Q/K projection GEMM, fp32 inputs -> bf16 outputs.
// (unchanged from verified version)
// ---------------------------------------------------------------------------
__global__ __launch_bounds__(256) void proj_kernel(
    const float* __restrict__ X,
    const float* __restrict__ Wq, const float* __restrict__ bq,
    const float* __restrict__ Wk, const float* __restrict__ bk,
    unsigned short* __restrict__ Qb, unsigned short* __restrict__ Kb)
{
    __shared__ unsigned short As[64][40];    // 64 rows x 32 bf16 (+pad)
    __shared__ unsigned short Bs[128][40];   // 128 rows x 32 bf16 (+pad)

    const float* __restrict__ W    = blockIdx.z ? Wk : Wq;
    const float* __restrict__ bias = blockIdx.z ? bk : bq;
    unsigned short* __restrict__ out = blockIdx.z ? Kb : Qb;

    const int t    = threadIdx.x;
    const int M0   = blockIdx.x * 64;
    const int N0   = blockIdx.y * 128;
    const int lane = t & 63;
    const int wave = t >> 6;
    const int wm   = (wave >> 1) * 32;   // wave row offset (0 or 32)
    const int wn   = (wave & 1) * 64;    // wave col offset (0 or 64)

    const int arow = t >> 2;
    const int acol = (t & 3) * 8;
    const int brow = t >> 1;
    const int bcol = (t & 1) * 16;

    f32x4 acc[2][4] = {};

    for (int kt = 0; kt < EMB_DIM / 32; ++kt) {
        const int k0 = kt * 32;
        {
            const float4* srcA = (const float4*)(X + (size_t)(M0 + arow) * EMB_DIM + k0 + acol);
            float4 va0 = srcA[0], va1 = srcA[1];
            unsigned int pa[4];
            pa[0] = (unsigned int)f2bf(va0.x) | ((unsigned int)f2bf(va0.y) << 16);
            pa[1] = (unsigned int)f2bf(va0.z) | ((unsigned int)f2bf(va0.w) << 16);
            pa[2] = (unsigned int)f2bf(va1.x) | ((unsigned int)f2bf(va1.y) << 16);
            pa[3] = (unsigned int)f2bf(va1.z) | ((unsigned int)f2bf(va1.w) << 16);
            *(uint4*)&As[arow][acol] = make_uint4(pa[0], pa[1], pa[2], pa[3]);

            const float4* srcB = (const float4*)(W + (size_t)(N0 + brow) * EMB_DIM + k0 + bcol);
            unsigned int pb[8];
            #pragma unroll
            for (int c = 0; c < 4; ++c) {
                float4 vb = srcB[c];
                pb[c * 2 + 0] = (unsigned int)f2bf(vb.x) | ((unsigned int)f2bf(vb.y) << 16);
                pb[c * 2 + 1] = (unsigned int)f2bf(vb.z) | ((unsigned int)f2bf(vb.w) << 16);
            }
            uint4* dstB = (uint4*)&Bs[brow][bcol];
            dstB[0] = make_uint4(pb[0], pb[1], pb[2], pb[3]);
            dstB[1] = make_uint4(pb[4], pb[5], pb[6], pb[7]);
        }
        __syncthreads();

        bf16x8 af[2], bff[4];
        #pragma unroll
        for (int i = 0; i < 2; ++i)
            af[i] = __builtin_bit_cast(bf16x8,
                *(const uint4*)&As[wm + i * 16 + (lane & 15)][(lane >> 4) * 8]);
        #pragma unroll
        for (int i = 0; i < 4; ++i)
            bff[i] = __builtin_bit_cast(bf16x8,
                *(const uint4*)&Bs[wn + i * 16 + (lane & 15)][(lane >> 4) * 8]);

        #pragma unroll
        for (int mi = 0; mi < 2; ++mi)
            #pragma unroll
            for (int ni = 0; ni < 4; ++ni)
                acc[mi][ni] = __builtin_amdgcn_mfma_f32_16x16x32_bf16(
                    af[mi], bff[ni], acc[mi][ni], 0, 0, 0);
        __syncthreads();
    }

    // epilogue: +bias, fp32 -> bf16. C/D map: col=lane&15, row=(lane>>4)*4+r
    #pragma unroll
    for (int mi = 0; mi < 2; ++mi) {
        #pragma unroll
        for (int ni = 0; ni < 4; ++ni) {
            const int col = N0 + wn + ni * 16 + (lane & 15);
            const float bval = bias[col];
            #pragma unroll
            for (int r = 0; r < 4; ++r) {
                const int row = M0 + wm + mi * 16 + (lane >> 4) * 4 + r;
                out[(size_t)row * EMB_DIM + col] = f2bf(acc[mi][ni][r] + bval);
            }
        }
    }
}

// ---------------------------------------------------------------------------
// Kernel 2: early-NT-zero scatter. One block per output row (h, n).
//
// Structure (derived from R0-R7 evidence):
//  * The 16 KB row of zeros is NT-stored DIRECTLY to global, issued in the
//    first ~1k cycles of the block (dependency-free, like the 6.2 TB/s fill
//    kernel). NT = no L2 allocate, so the L2/L3-resident Kb/Qb/sidx stay
//    hot for the gather (R2 proved plain direct stores cost ~130 us of
//    pollution; R4/R5 A/B proved NT > plain by 24 us even when LDS-staged).
//  * tickets/gather/dots run UNDER the zero-store drain. Tags (LDS
//    atomicMax, last-occurrence-wins) are never overwritten -> only 2
//    barriers, no 16 KB LDS row, no readback.
//  * __syncthreads() #2 performs the documented vmcnt(0)+lgkmcnt(0) drain
//    before s_barrier: all waves' zeros are acked at the coherence point
//    AND all tickets visible. The <=128 winning score dwords are then
//    NT-stored; same-address writes arrive later at the same HBM channel
//    -> score wins (last-write-wins preserved).
//  * Load-ordering: sidx/Q loads issue BEFORE the zero stores; gather
//    loads are pinned before the stores by sched_barrier(0). vmcnt waits
//    for the dots therefore target loads OLDER than all outstanding
//    stores -> no store drain on the compute path (in-order retirement).
// ---------------------------------------------------------------------------
__global__ __launch_bounds__(256) void scatter_kernel(
    const unsigned short* __restrict__ Qb,
    const unsigned short* __restrict__ Kb,
    const int* __restrict__ sidx,
    float* __restrict__ out)
{
    __shared__ unsigned int tags[N_NODES];   // 16 KB ticket array (read-only after tickets)
    __shared__ int sIdx[K_SPARSE];

    const int t = threadIdx.x;
    const int b = blockIdx.x;
    const int h = b >> 12;
    const int n = b & (N_NODES - 1);
    const int j = t & 7;            // sector lane within 8-lane key group

    // ---- phase 1: independent global loads (OLDER than all stores) ----
    const uint4 qu = *(const uint4*)(Qb + (size_t)n * EMB_DIM + h * HEAD_DIM + j * 8);
    int myIdxLd = 0;
    if (t < K_SPARSE)
        myIdxLd = sidx[(size_t)b * K_SPARSE + t];

    // ---- phase 2: zero tag array, publish indices ----
    uint4* tagv = (uint4*)tags;
    const uint4 zu = make_uint4(0u, 0u, 0u, 0u);
    #pragma unroll
    for (int i = 0; i < 4; ++i) tagv[t + 256 * i] = zu;
    if (t < K_SPARSE) sIdx[t] = myIdxLd;

    // unpack this lane's 8 Q values
    float q[8];
    {
        unsigned int uu[4] = {qu.x, qu.y, qu.z, qu.w};
        #pragma unroll
        for (int w = 0; w < 4; ++w) {
            q[2 * w + 0] = bf2f((unsigned short)(uu[w] & 0xffffu));
            q[2 * w + 1] = bf2f((unsigned short)(uu[w] >> 16));
        }
    }
    __syncthreads();   // [1] tags zeroed + sIdx visible (no stores outstanding yet)

    // ---- phase 3: tickets (last occurrence wins) ----
    if (t < K_SPARSE) atomicMax(&tags[myIdxLd], (unsigned int)(t + 1));

    // ---- phase 4: gather loads issue (still OLDER than the zero stores) ----
    float* orow = out + (size_t)b * N_NODES;
    int   kidx[4];
    uint4 u[4];
    #pragma unroll
    for (int p = 0; p < 4; ++p) {
        const int kk = (t >> 3) + 32 * p;
        kidx[p] = sIdx[kk];
        u[p] = *(const uint4*)(Kb + (size_t)kidx[p] * EMB_DIM + h * HEAD_DIM + j * 8);
    }
    __builtin_amdgcn_sched_barrier(0);

    // ---- phase 5: NT zero stores of the whole row -- the 16 KB of
    //      mandatory HBM writes starts draining NOW, under phases 6-7 ----
    f32x4* orowv = (f32x4*)orow;
    const f32x4 z4 = {0.0f, 0.0f, 0.0f, 0.0f};
    #pragma unroll
    for (int i = 0; i < 4; ++i)
        __builtin_nontemporal_store(z4, &orowv[t + 256 * i]);
    __builtin_amdgcn_sched_barrier(0);

    // ---- phase 6: dots (waits target u[] loads, older than the stores) ----
    float score[4];
    #pragma unroll
    for (int p = 0; p < 4; ++p) {
        unsigned int uu[4] = {u[p].x, u[p].y, u[p].z, u[p].w};
        float acc = 0.0f;
        #pragma unroll
        for (int w = 0; w < 4; ++w) {
            acc += bf2f((unsigned short)(uu[w] & 0xffffu)) * q[2 * w + 0];
            acc += bf2f((unsigned short)(uu[w] >> 16))     * q[2 * w + 1];
        }
        acc += __shfl_xor(acc, 1);
        acc += __shfl_xor(acc, 2);
        acc += __shfl_xor(acc, 4);
        score[p] = acc * 0.125f;   // 1/sqrt(64)
    }

    // ---- phase 7: full drain barrier: vmcnt(0) -> every wave's zeros are
    //      acked at the coherence point; lgkmcnt(0) -> tickets visible ----
    __syncthreads();   // [2]

    // ---- phase 8: winners NT-scatter their score dwords (arrive at the
    //      HBM channel strictly after the acked zeros -> last write wins) ----
    #pragma unroll
    for (int p = 0; p < 4; ++p) {
        const int kk = (t >> 3) + 32 * p;
        if (j == 0 && tags[kidx[p]] == (unsigned int)(kk + 1))
            __builtin_nontemporal_store(score[p], &orow[kidx[p]]);
    }
}

extern "C" void kernel_launch(void* const* d_in, const int* in_sizes, int n_in,
                              void* d_out, int out_size, void* d_ws, size_t ws_size,
                              hipStream_t stream) {
    const float* emb = (const float*)d_in[0];
    const float* Wq  = (const float*)d_in[1];
    const float* bq  = (const float*)d_in[2];
    const float* Wk  = (const float*)d_in[3];
    const float* bk  = (const float*)d_in[4];
    const int*   si  = (const int*)d_in[5];
    float* out = (float*)d_out;

    // workspace: Qb (4 MB) + Kb (4 MB) bf16
    unsigned short* Qb = (unsigned short*)d_ws;
    unsigned short* Kb = Qb + (size_t)N_NODES * EMB_DIM;

    dim3 pg(N_NODES / 64, EMB_DIM / 128, 2);   // 64 x 4 x 2 = 512 blocks
    proj_kernel<<<pg, 256, 0, stream>>>(emb, Wq, bq, Wk, bk, Qb, Kb);

    scatter_kernel<<<N_HEADS * N_NODES, 256, 0, stream>>>(Qb, Kb, si, out);
}